// Round 7
// baseline (213.609 us; speedup 1.0000x reference)
//
#include <hip/hip_runtime.h>
#include <hip/hip_bf16.h>

// Problem constants
#define BB 16
#define CC 64
#define HH 64
#define WW 64
#define QQ 8192
#define HID 256
#define KK 576            // C*9
#define HT 66             // H + 2 halo
#define FROW 264          // 257 channels padded to 264 (16B-aligned rows)

typedef short short8 __attribute__((ext_vector_type(8)));
typedef short sv4    __attribute__((ext_vector_type(4)));
typedef float f32x4  __attribute__((ext_vector_type(4)));

__device__ __forceinline__ short f2bf(float f) {
    union { float f; unsigned u; } v; v.f = f;
    unsigned r = v.u + 0x7fffu + ((v.u >> 16) & 1u);
    return (short)(r >> 16);
}
__device__ __forceinline__ float bf2f(short s) {
    union { unsigned u; float f; } v; v.u = ((unsigned)(unsigned short)s) << 16;
    return v.f;
}
// Barrier that only drains LDS (lgkmcnt) — does NOT force vmcnt(0).
__device__ __forceinline__ void barrier_lds() {
    asm volatile("s_waitcnt lgkmcnt(0)" ::: "memory");
    __builtin_amdgcn_s_barrier();
    asm volatile("" ::: "memory");
}
// Async global->LDS DMA, 16B per lane.
__device__ __forceinline__ void glld16(const short* g, short* l) {
    __builtin_amdgcn_global_load_lds(
        (const __attribute__((address_space(1))) void*)g,
        (__attribute__((address_space(3))) void*)l, 16, 0, 0);
}

// ---------------------------------------------------------------------------
// R4 structure restored (proven 146.7us). This round adds ABLATION variants
// of mlp_k (template<int VAR>) launched into dead workspace AFTER the real
// pipeline, to localize mlp's ~25us unattributed stall via the profile
// table. VAR: 0=real, 1=no-F-gather, 2=no-w2/no-MFMA, 3=gather-only.
// ---------------------------------------------------------------------------

// Kernel T+P fused: feat transpose + weight repack. XCD x writes image
// x+8's rows first, then image x (matches conv's consumption order).
__global__ __launch_bounds__(256) void prep_transpose_k(const float* __restrict__ feat,
                                                        const float* __restrict__ w2,
                                                        const float* __restrict__ w3,
                                                        const float* __restrict__ b3,
                                                        short* __restrict__ featT,
                                                        short* __restrict__ w3cB,
                                                        short* __restrict__ w2cB) {
    __shared__ float ftile[64][65];
    const int t = threadIdx.x;
    const int gidx = blockIdx.x * 256 + t;   // grid = 1056 wgs (raw index)

    if (gidx < 156672) {                      // 72 kchunks * 272 n * 8
        int kchunk = gidx / 2176;
        int rem = gidx - kchunk * 2176;
        int n = rem >> 3, j = rem & 7;
        int kglob = kchunk * 8 + j;
        int pos = kglob >> 6, c = kglob & 63;
        float v = 0.f;
        if (n < 256)      v = w3[n * KK + c * 9 + pos];
        else if (n == 256) v = b3[c * 9 + pos];
        w3cB[gidx] = f2bf(v);
    }
    if (gidx < 65536) {                       // 32 kchunks * 256 n * 8
        int kchunk = gidx >> 11;
        int rem = gidx & 2047;
        int n = rem >> 3, j = rem & 7;
        int k = kchunk * 8 + j;
        w2cB[gidx] = f2bf(w2[k * 256 + n]);
    }

    const int x = blockIdx.x & 7;
    const int i = blockIdx.x >> 3;            // 0..131
    const int b  = (i < 66) ? (x + 8) : x;
    const int yy = (i < 66) ? i : (i - 66);
    short* out_row = featT + ((b * HT + yy) * HT) * 64;

    if (yy == 0 || yy == HT - 1) {
        for (int idx = t; idx < HT * 64; idx += 256) out_row[idx] = 0;
        return;
    }
    const int y = yy - 1;
    const float* src = feat + ((b * CC) * HH + y) * WW;
#pragma unroll
    for (int i2 = 0; i2 < 16; ++i2) {
        int idx = i2 * 256 + t;
        int c = idx >> 6, xx = idx & 63;
        ftile[c][xx] = src[c * (HH * WW) + xx];
    }
    if (t < 64) out_row[t] = 0;
    else if (t < 128) out_row[(HT - 1) * 64 + (t - 64)] = 0;
    __syncthreads();
#pragma unroll
    for (int i2 = 0; i2 < 16; ++i2) {
        int idx = i2 * 256 + t;
        int xx = idx >> 6, c = idx & 63;
        out_row[(xx + 1) * 64 + c] = f2bf(ftile[c][xx]);
    }
}

// ---------------------------------------------------------------------------
// Kernel C v7 + XCD swizzle (R4 exact): barrier-free K-loop, B streamed
// L2->regs. XCD x: image x+8 first, then x (LIFO vs mlp).
// ---------------------------------------------------------------------------
#define SSTR 72   // slab row stride (shorts): 144B, 16B-aligned, free 2-way
__global__ __launch_bounds__(256, 2) void conv_k(const short* __restrict__ featT,
                                                 const short* __restrict__ w3cB,
                                                 short* __restrict__ F) {
    __shared__ short slab[3 * HT * SSTR];   // 14,256 shorts = 28,512 B
    const int t = threadIdx.x;
    const int wave = t >> 6, lane = t & 63, quad = lane >> 4, ln16 = lane & 15;
    const int x = blockIdx.x & 7;
    const int i0 = blockIdx.x >> 3;         // 0..127
    const int b = (i0 < 64) ? (x + 8) : x;
    const int y = i0 & 63;

    f32x4 acc[4][5];
#pragma unroll
    for (int a = 0; a < 4; ++a)
#pragma unroll
        for (int i = 0; i < 5; ++i) acc[a][i] = (f32x4){0.f, 0.f, 0.f, 0.f};

    short8 bbuf[3][5];
    const short* bbase = w3cB + (quad * 272 + ln16) * 8;
    auto loadB = [&](int st, int slot) {
#pragma unroll
        for (int i = 0; i < 5; ++i) {
            int sub = (i < 4) ? (wave + 4 * i) : 16;
            bbuf[slot][i] = *(const short8*)(bbase + st * 8704 + sub * 128);
        }
    };

    loadB(0, 0);    // in flight during slab staging
    loadB(1, 1);

    const short* slabsrc = featT + b * (HT * HT * 64) + y * (HT * 64);
#pragma unroll
    for (int it = 0; it < 7; ++it) {
        int i = it * 256 + t;               // 1584 chunks of 8 shorts
        if (i < 1584) {
            short8 v = *(const short8*)(slabsrc + i * 8);
            int row = i >> 3, cs = (i & 7) * 8;
            *(short8*)(&slab[row * SSTR + cs]) = v;
        }
    }
    barrier_lds();   // slab visible; bbuf loads stay in flight

#pragma unroll
    for (int st = 0; st < 18; ++st) {
        if (st < 16) loadB(st + 2, (st + 2) % 3);
        const int pos = st >> 1, ks = st & 1;
        const int di = pos / 3, dj = pos - di * 3;
        short8 af[4];
#pragma unroll
        for (int ms = 0; ms < 4; ++ms)
            af[ms] = *(const short8*)(&slab[(di * HT + ms * 16 + ln16 + dj) * SSTR + ks * 32 + quad * 8]);
#pragma unroll
        for (int i = 0; i < 5; ++i)
#pragma unroll
            for (int ms = 0; ms < 4; ++ms)
                acc[ms][i] = __builtin_amdgcn_mfma_f32_16x16x32_bf16(af[ms], bbuf[st % 3][i], acc[ms][i], 0, 0, 0);
    }

#pragma unroll
    for (int h = 0; h < 2; ++h) {
        if (h) barrier_lds();   // h=0's slab reads done before overwrite
#pragma unroll
        for (int i = 0; i < 5; ++i) {
            int sub = (i < 4) ? (wave + 4 * i) : 16;
            int n = sub * 16 + ln16;
            bool store = (i < 4) || (wave == 0 && n < FROW);
            if (store) {
#pragma unroll
                for (int ms2 = 0; ms2 < 2; ++ms2) {
                    int ms = h * 2 + ms2;
#pragma unroll
                    for (int r = 0; r < 4; ++r) {
                        int xl = ms2 * 16 + quad * 4 + r;   // local row 0..31
                        slab[xl * FROW + n] = f2bf(acc[ms][i][r]);
                    }
                }
            }
        }
        barrier_lds();
        short8* dst = (short8*)(F + ((long)(b * 64 + y) * 64 + h * 32) * FROW);
        const short8* src8 = (const short8*)slab;
#pragma unroll
        for (int it = 0; it < 5; ++it) {
            int idx = it * 256 + t;
            if (idx < (32 * FROW) / 8) dst[idx] = src8[idx];
        }
    }
}

// ---------------------------------------------------------------------------
// Kernel M (R4 v10 body) with ablation template.
//   VAR=0: real (FLds DMA staging + XCD phase swizzle) — R4 exact.
//   VAR=1: F staging + fbs removed (DMA skipped, FLds zero-filled cheaply).
//   VAR=2: w2 stream + MFMA removed (acc2=0; hf reads kept alive).
//   VAR=3: gather-only (coord -> lin -> F DMA -> reduce -> store).
// ---------------------------------------------------------------------------
template <int VAR>
__global__ __launch_bounds__(256, 2) void mlp_k(const float* __restrict__ coord,
                                                const float* __restrict__ cell,
                                                const float* __restrict__ w1,
                                                const float* __restrict__ b1,
                                                const float* __restrict__ b2v,
                                                const short* __restrict__ w2cB,
                                                const short* __restrict__ F,
                                                float* __restrict__ out) {
    __shared__ short HhF[16384];    // 32,768 B: H1 fragment-major
    __shared__ short FLds[16384];   // 32,768 B: F rows, col-swizzled

    const int t = threadIdx.x;
    const int wave = t >> 6, lane = t & 63, quad = lane >> 4, ln16 = lane & 15;
    const int xcd = blockIdx.x & 7;
    const int i0 = blockIdx.x >> 3;         // 0..255
    const int b  = (i0 < 128) ? xcd : (xcd + 8);
    const int qi = i0 & 127;
    const int qbase = b * QQ + qi * 64;

    short8 wbuf[3][4];
    const short* w2base = w2cB + (quad * 256 + wave * 64 + ln16) * 8;
    auto loadW = [&](int s, int slot) {
#pragma unroll
        for (int i = 0; i < 4; ++i)
            wbuf[slot][i] = *(const short8*)(w2base + s * 8192 + i * 128);
    };

    const int g = qbase + lane;
    const float2 cc = *(const float2*)(coord + g * 2);
    const float2 ce = *(const float2*)(cell + g * 2);

    if constexpr (VAR != 2 && VAR != 3) { loadW(0, 0); loadW(1, 1); }

    const float coy = cc.x - ce.x * 0.5f, cox = cc.y - ce.y * 0.5f;
    const float cqy = fminf(fmaxf(coy + 1e-6f, -0.999999f), 0.999999f);
    const float cqx = fminf(fmaxf(cox + 1e-6f, -0.999999f), 0.999999f);
    int iy = (int)rintf(((cqy + 1.0f) * 64.0f - 1.0f) * 0.5f); iy = min(max(iy, 0), 63);
    int ix = (int)rintf(((cqx + 1.0f) * 64.0f - 1.0f) * 0.5f); ix = min(max(ix, 0), 63);
    const int lin = iy * 64 + ix;
    const float in0 = (coy - ((float)iy * (1.0f / 32.0f) - 1.0f)) * 32.0f;
    const float in1 = (cox - ((float)ix * (1.0f / 32.0f) - 1.0f)) * 32.0f;
    const float in2 = ce.x * 32.0f;

    const short* Fb = F + (long)b * 4096 * FROW;
    short fbs = 0;
    if constexpr (VAR != 1) fbs = Fb[(long)lin * FROW + 256];

    // --- F row staging via DMA (VAR 0,2,3); VAR 1 keeps addresses alive ---
    if constexpr (VAR != 1) {
#pragma unroll
        for (int j = 0; j < 8; ++j) {
            const int r = 2 * (wave * 8 + j) + (lane >> 5);
            const int linr = __shfl(lin, r, 64);
            const int colb = ((lane & 31) * 16) ^ ((r & 7) << 4);
            glld16(Fb + (long)linr * FROW + (colb >> 1), &FLds[(wave * 8 + j) * 512]);
        }
    } else {
        // keep lin/Fb dataflow live without issuing the gather (rule #17)
        int lv = lin; asm volatile("" :: "v"(lv), "v"((int)(long)Fb));
        if (t < 64) *(short8*)(&FLds[t * 256]) = (short8){0,0,0,0,0,0,0,0};
    }

    float part[4] = {0.f, 0.f, 0.f, 0.f};
    f32x4 b2q[4];
#pragma unroll
    for (int i = 0; i < 4; ++i) b2q[i] = (f32x4){0.f, 0.f, 0.f, 0.f};
    f32x4 acc2[4][4];
#pragma unroll
    for (int i = 0; i < 4; ++i)
#pragma unroll
        for (int ms = 0; ms < 4; ++ms) acc2[i][ms] = (f32x4){0.f, 0.f, 0.f, 0.f};

    if constexpr (VAR != 3) {
        // --- H1 ---
        short8 hv[8];
        const int k0w = wave * 64;
#pragma unroll
        for (int c8 = 0; c8 < 8; ++c8) {
            const int k0 = k0w + c8 * 8;
            f32x4 wa0 = *(const f32x4*)(w1 + k0),       wa1 = *(const f32x4*)(w1 + k0 + 4);
            f32x4 wb0 = *(const f32x4*)(w1 + 256 + k0), wb1 = *(const f32x4*)(w1 + 256 + k0 + 4);
            f32x4 wc0 = *(const f32x4*)(w1 + 512 + k0), wc1 = *(const f32x4*)(w1 + 512 + k0 + 4);
            f32x4 bb0 = *(const f32x4*)(b1 + k0),       bb1 = *(const f32x4*)(b1 + k0 + 4);
#pragma unroll
            for (int jj = 0; jj < 4; ++jj) {
                float v0 = fmaf(in0, wa0[jj], fmaf(in1, wb0[jj], fmaf(in2, wc0[jj], bb0[jj])));
                float v1 = fmaf(in0, wa1[jj], fmaf(in1, wb1[jj], fmaf(in2, wc1[jj], bb1[jj])));
                hv[c8][jj]     = f2bf(fmaxf(v0, 0.f));
                hv[c8][jj + 4] = f2bf(fmaxf(v1, 0.f));
            }
        }
#pragma unroll
        for (int c8 = 0; c8 < 8; ++c8)
            *(short8*)(&HhF[((2 * wave + (c8 >> 2)) * 4 + (c8 & 3)) * 512 + lane * 8]) = hv[c8];
        barrier_lds();   // HhF visible; F DMA + wbuf stay in flight

        // --- H2^T MFMA loop ---
#pragma unroll
        for (int s = 0; s < 8; ++s) {
            if constexpr (VAR != 2) { if (s < 6) loadW(s + 2, (s + 2) % 3); }
            short8 hf[4];
#pragma unroll
            for (int ms = 0; ms < 4; ++ms)
                hf[ms] = *(const short8*)(&HhF[(s * 4 + quad) * 512 + (ms * 16 + ln16) * 8]);
            if (s == 7) {
#pragma unroll
                for (int i = 0; i < 4; ++i)
                    b2q[i] = *(const f32x4*)(b2v + wave * 64 + i * 16 + quad * 4);
            }
            if constexpr (VAR != 2) {
#pragma unroll
                for (int i = 0; i < 4; ++i)
#pragma unroll
                    for (int ms = 0; ms < 4; ++ms)
                        acc2[i][ms] = __builtin_amdgcn_mfma_f32_16x16x32_bf16(wbuf[s % 3][i], hf[ms], acc2[i][ms], 0, 0, 0);
            } else {
                // keep the ds_reads live without MFMA (rule #17)
#pragma unroll
                for (int ms = 0; ms < 4; ++ms)
                    asm volatile("" :: "v"(hf[ms][0]), "v"(hf[ms][7]));
            }
        }
    }

    __syncthreads();   // drains F DMA + cross-wave visibility

    // --- combine ---
    const float fbv = bf2f(fbs);
    const char* FLb = (const char*)FLds;
#pragma unroll
    for (int ms = 0; ms < 4; ++ms) {
        const int r = ms * 16 + ln16;
        const int xr = (r & 7) << 4;
        const int rb = r * 512;
#pragma unroll
        for (int i = 0; i < 4; ++i) {
            sv4 fvv = *(const sv4*)(FLb + rb + ((wave * 128 + i * 32 + quad * 8) ^ xr));
#pragma unroll
            for (int r4 = 0; r4 < 4; ++r4)
                part[ms] = fmaf(fmaxf(acc2[i][ms][r4] + b2q[i][r4], 0.f), bf2f(fvv[r4]), part[ms]);
        }
    }
#pragma unroll
    for (int ms = 0; ms < 4; ++ms) {
        part[ms] += __shfl_xor(part[ms], 16, 64);
        part[ms] += __shfl_xor(part[ms], 32, 64);
    }
    barrier_lds();                        // all FLds reads done before aliasing
    float* red = (float*)FLds;            // red[64][4] aliased into FLds
    if (quad == 0) {
#pragma unroll
        for (int ms = 0; ms < 4; ++ms) red[(ms * 16 + ln16) * 4 + wave] = part[ms];
    }
    barrier_lds();
    if (t < 64)
        out[qbase + t] = red[t * 4 + 0] + red[t * 4 + 1] + red[t * 4 + 2] + red[t * 4 + 3] + fbv;
}

// ---------------------------------------------------------------------------
extern "C" void kernel_launch(void* const* d_in, const int* in_sizes, int n_in,
                              void* d_out, int out_size, void* d_ws, size_t ws_size,
                              hipStream_t stream) {
    const float* feat  = (const float*)d_in[0];
    const float* coord = (const float*)d_in[1];
    const float* cell  = (const float*)d_in[2];
    const float* w1    = (const float*)d_in[3];
    const float* b1    = (const float*)d_in[4];
    const float* w2    = (const float*)d_in[5];
    const float* b2    = (const float*)d_in[6];
    const float* w3    = (const float*)d_in[7];
    const float* b3    = (const float*)d_in[8];
    float* out = (float*)d_out;

    char* ws = (char*)d_ws;
    short* w3cB  = (short*)(ws);                       // 72*2176*2      = 313,344
    short* w2cB  = (short*)(ws + 313344);              // 32*2048*2      = 131,072
    short* featT = (short*)(ws + 444416);              // 16*66*66*64*2  = 8,921,088
    short* F     = (short*)(ws + 9365504);             // 16*4096*264*2  = 34,603,008
    float* scratch = (float*)(ws + 444416);            // featT dead after conv+real mlp
    (void)ws_size; (void)in_sizes; (void)n_in; (void)out_size;

    prep_transpose_k<<<BB * HT, 256, 0, stream>>>(feat, w2, w3, b3, featT, w3cB, w2cB);
    conv_k<<<BB * HH, 256, 0, stream>>>(featT, w3cB, F);
    mlp_k<0><<<(BB * QQ) / 64, 256, 0, stream>>>(coord, cell, w1, b1, b2, w2cB, F, out);
    // --- ablation probes (write to dead workspace; out already correct) ---
    mlp_k<1><<<(BB * QQ) / 64, 256, 0, stream>>>(coord, cell, w1, b1, b2, w2cB, F, scratch);
    mlp_k<2><<<(BB * QQ) / 64, 256, 0, stream>>>(coord, cell, w1, b1, b2, w2cB, F, scratch);
    mlp_k<3><<<(BB * QQ) / 64, 256, 0, stream>>>(coord, cell, w1, b1, b2, w2cB, F, scratch);
}

// Round 8
// 143.841 us; speedup vs baseline: 1.4850x; 1.4850x over previous
//
#include <hip/hip_runtime.h>
#include <hip/hip_bf16.h>

// Problem constants
#define BB 16
#define CC 64
#define HH 64
#define WW 64
#define QQ 8192
#define HID 256
#define KK 576            // C*9
#define HT 66             // H + 2 halo
#define FROW 264          // 257 channels padded to 264 (16B-aligned rows)

typedef short short8 __attribute__((ext_vector_type(8)));
typedef short sv4    __attribute__((ext_vector_type(4)));
typedef float f32x4  __attribute__((ext_vector_type(4)));

__device__ __forceinline__ short f2bf(float f) {
    union { float f; unsigned u; } v; v.f = f;
    unsigned r = v.u + 0x7fffu + ((v.u >> 16) & 1u);
    return (short)(r >> 16);
}
__device__ __forceinline__ float bf2f(short s) {
    union { unsigned u; float f; } v; v.u = ((unsigned)(unsigned short)s) << 16;
    return v.f;
}
// Barrier that only drains LDS (lgkmcnt) — does NOT force vmcnt(0).
__device__ __forceinline__ void barrier_lds() {
    asm volatile("s_waitcnt lgkmcnt(0)" ::: "memory");
    __builtin_amdgcn_s_barrier();
    asm volatile("" ::: "memory");
}
// Async global->LDS DMA, 16B per lane.
__device__ __forceinline__ void glld16(const short* g, short* l) {
    __builtin_amdgcn_global_load_lds(
        (const __attribute__((address_space(1))) void*)g,
        (__attribute__((address_space(3))) void*)l, 16, 0, 0);
}

// ---------------------------------------------------------------------------
// Kernel T+P fused: feat transpose + weight repack. XCD x writes image
// x+8's rows first, then image x (matches conv's consumption order).
// ---------------------------------------------------------------------------
__global__ __launch_bounds__(256) void prep_transpose_k(const float* __restrict__ feat,
                                                        const float* __restrict__ w2,
                                                        const float* __restrict__ w3,
                                                        const float* __restrict__ b3,
                                                        short* __restrict__ featT,
                                                        short* __restrict__ w3cB,
                                                        short* __restrict__ w2cB) {
    __shared__ float ftile[64][65];
    const int t = threadIdx.x;
    const int gidx = blockIdx.x * 256 + t;   // grid = 1056 wgs (raw index)

    if (gidx < 156672) {                      // 72 kchunks * 272 n * 8
        int kchunk = gidx / 2176;
        int rem = gidx - kchunk * 2176;
        int n = rem >> 3, j = rem & 7;
        int kglob = kchunk * 8 + j;
        int pos = kglob >> 6, c = kglob & 63;
        float v = 0.f;
        if (n < 256)      v = w3[n * KK + c * 9 + pos];
        else if (n == 256) v = b3[c * 9 + pos];
        w3cB[gidx] = f2bf(v);
    }
    if (gidx < 65536) {                       // 32 kchunks * 256 n * 8
        int kchunk = gidx >> 11;
        int rem = gidx & 2047;
        int n = rem >> 3, j = rem & 7;
        int k = kchunk * 8 + j;
        w2cB[gidx] = f2bf(w2[k * 256 + n]);
    }

    const int x = blockIdx.x & 7;
    const int i = blockIdx.x >> 3;            // 0..131
    const int b  = (i < 66) ? (x + 8) : x;
    const int yy = (i < 66) ? i : (i - 66);
    short* out_row = featT + ((b * HT + yy) * HT) * 64;

    if (yy == 0 || yy == HT - 1) {
        for (int idx = t; idx < HT * 64; idx += 256) out_row[idx] = 0;
        return;
    }
    const int y = yy - 1;
    const float* src = feat + ((b * CC) * HH + y) * WW;
#pragma unroll
    for (int i2 = 0; i2 < 16; ++i2) {
        int idx = i2 * 256 + t;
        int c = idx >> 6, xx = idx & 63;
        ftile[c][xx] = src[c * (HH * WW) + xx];
    }
    if (t < 64) out_row[t] = 0;
    else if (t < 128) out_row[(HT - 1) * 64 + (t - 64)] = 0;
    __syncthreads();
#pragma unroll
    for (int i2 = 0; i2 < 16; ++i2) {
        int idx = i2 * 256 + t;
        int xx = idx >> 6, c = idx & 63;
        out_row[(xx + 1) * 64 + c] = f2bf(ftile[c][xx]);
    }
}

// ---------------------------------------------------------------------------
// Kernel C v7 + XCD swizzle (R4 exact): barrier-free K-loop, B streamed
// L2->regs. XCD x: image x+8 first, then x (LIFO vs mlp).
// ---------------------------------------------------------------------------
#define SSTR 72   // slab row stride (shorts): 144B, 16B-aligned, free 2-way
__global__ __launch_bounds__(256, 2) void conv_k(const short* __restrict__ featT,
                                                 const short* __restrict__ w3cB,
                                                 short* __restrict__ F) {
    __shared__ short slab[3 * HT * SSTR];   // 14,256 shorts = 28,512 B
    const int t = threadIdx.x;
    const int wave = t >> 6, lane = t & 63, quad = lane >> 4, ln16 = lane & 15;
    const int x = blockIdx.x & 7;
    const int i0 = blockIdx.x >> 3;         // 0..127
    const int b = (i0 < 64) ? (x + 8) : x;
    const int y = i0 & 63;

    f32x4 acc[4][5];
#pragma unroll
    for (int a = 0; a < 4; ++a)
#pragma unroll
        for (int i = 0; i < 5; ++i) acc[a][i] = (f32x4){0.f, 0.f, 0.f, 0.f};

    short8 bbuf[3][5];
    const short* bbase = w3cB + (quad * 272 + ln16) * 8;
    auto loadB = [&](int st, int slot) {
#pragma unroll
        for (int i = 0; i < 5; ++i) {
            int sub = (i < 4) ? (wave + 4 * i) : 16;
            bbuf[slot][i] = *(const short8*)(bbase + st * 8704 + sub * 128);
        }
    };

    loadB(0, 0);    // in flight during slab staging
    loadB(1, 1);

    const short* slabsrc = featT + b * (HT * HT * 64) + y * (HT * 64);
#pragma unroll
    for (int it = 0; it < 7; ++it) {
        int i = it * 256 + t;               // 1584 chunks of 8 shorts
        if (i < 1584) {
            short8 v = *(const short8*)(slabsrc + i * 8);
            int row = i >> 3, cs = (i & 7) * 8;
            *(short8*)(&slab[row * SSTR + cs]) = v;
        }
    }
    barrier_lds();   // slab visible; bbuf loads stay in flight

#pragma unroll
    for (int st = 0; st < 18; ++st) {
        if (st < 16) loadB(st + 2, (st + 2) % 3);
        const int pos = st >> 1, ks = st & 1;
        const int di = pos / 3, dj = pos - di * 3;
        short8 af[4];
#pragma unroll
        for (int ms = 0; ms < 4; ++ms)
            af[ms] = *(const short8*)(&slab[(di * HT + ms * 16 + ln16 + dj) * SSTR + ks * 32 + quad * 8]);
#pragma unroll
        for (int i = 0; i < 5; ++i)
#pragma unroll
            for (int ms = 0; ms < 4; ++ms)
                acc[ms][i] = __builtin_amdgcn_mfma_f32_16x16x32_bf16(af[ms], bbuf[st % 3][i], acc[ms][i], 0, 0, 0);
    }

#pragma unroll
    for (int h = 0; h < 2; ++h) {
        if (h) barrier_lds();   // h=0's slab reads done before overwrite
#pragma unroll
        for (int i = 0; i < 5; ++i) {
            int sub = (i < 4) ? (wave + 4 * i) : 16;
            int n = sub * 16 + ln16;
            bool store = (i < 4) || (wave == 0 && n < FROW);
            if (store) {
#pragma unroll
                for (int ms2 = 0; ms2 < 2; ++ms2) {
                    int ms = h * 2 + ms2;
#pragma unroll
                    for (int r = 0; r < 4; ++r) {
                        int xl = ms2 * 16 + quad * 4 + r;   // local row 0..31
                        slab[xl * FROW + n] = f2bf(acc[ms][i][r]);
                    }
                }
            }
        }
        barrier_lds();
        short8* dst = (short8*)(F + ((long)(b * 64 + y) * 64 + h * 32) * FROW);
        const short8* src8 = (const short8*)slab;
#pragma unroll
        for (int it = 0; it < 5; ++it) {
            int idx = it * 256 + t;
            if (idx < (32 * FROW) / 8) dst[idx] = src8[idx];
        }
    }
}

// ---------------------------------------------------------------------------
// Kernel M v12: QUEUE-ORDER INVERSION (fix for R7's measured zero overlap).
//   vmcnt retires IN ORDER, so any load issued after the F-gather DMAs
//   chains behind the full ~22us gather stream. v12 issues vmem in the
//   order: coord -> ALL 32 w2 loads (wbuf[8][4], full preload) -> H1's
//   w1/b1 loads -> F DMA + fbs LAST (sched_barrier-pinned). The MFMA loop
//   then contains NO vmem: wbuf waits retire only pre-gather loads, and
//   the gather drains under the whole loop, absorbed by __syncthreads.
//   b2q load moved after the loop (cuts peak VGPR; gather already drained).
// ---------------------------------------------------------------------------
__global__ __launch_bounds__(256, 2) void mlp_k(const float* __restrict__ coord,
                                                const float* __restrict__ cell,
                                                const float* __restrict__ w1,
                                                const float* __restrict__ b1,
                                                const float* __restrict__ b2v,
                                                const short* __restrict__ w2cB,
                                                const short* __restrict__ F,
                                                float* __restrict__ out) {
    __shared__ short HhF[16384];    // 32,768 B: H1 fragment-major
    __shared__ short FLds[16384];   // 32,768 B: F rows, col-swizzled

    const int t = threadIdx.x;
    const int wave = t >> 6, lane = t & 63, quad = lane >> 4, ln16 = lane & 15;
    const int xcd = blockIdx.x & 7;
    const int i0 = blockIdx.x >> 3;         // 0..255
    const int b  = (i0 < 128) ? xcd : (xcd + 8);
    const int qi = i0 & 127;
    const int qbase = b * QQ + qi * 64;

    // --- oldest vmem: coords ---
    const int g = qbase + lane;
    const float2 cc = *(const float2*)(coord + g * 2);
    const float2 ce = *(const float2*)(cell + g * 2);

    // --- FULL w2 preload: 32 independent 16B loads, ALL issued before the
    //     gather so no wbuf wait can chain behind it ---
    short8 wbuf[8][4];
    const short* w2base = w2cB + (quad * 256 + wave * 64 + ln16) * 8;
#pragma unroll
    for (int s = 0; s < 8; ++s)
#pragma unroll
        for (int i = 0; i < 4; ++i)
            wbuf[s][i] = *(const short8*)(w2base + s * 8192 + i * 128);
    __builtin_amdgcn_sched_barrier(0);   // pin: w2 issues stay above

    const float coy = cc.x - ce.x * 0.5f, cox = cc.y - ce.y * 0.5f;
    const float cqy = fminf(fmaxf(coy + 1e-6f, -0.999999f), 0.999999f);
    const float cqx = fminf(fmaxf(cox + 1e-6f, -0.999999f), 0.999999f);
    int iy = (int)rintf(((cqy + 1.0f) * 64.0f - 1.0f) * 0.5f); iy = min(max(iy, 0), 63);
    int ix = (int)rintf(((cqx + 1.0f) * 64.0f - 1.0f) * 0.5f); ix = min(max(ix, 0), 63);
    const int lin = iy * 64 + ix;
    const float in0 = (coy - ((float)iy * (1.0f / 32.0f) - 1.0f)) * 32.0f;
    const float in1 = (cox - ((float)ix * (1.0f / 32.0f) - 1.0f)) * 32.0f;
    const float in2 = ce.x * 32.0f;

    // --- H1 (w1/b1 loads issued here: still older than the gather) ---
    short8 hv[8];
    const int k0w = wave * 64;
#pragma unroll
    for (int c8 = 0; c8 < 8; ++c8) {
        const int k0 = k0w + c8 * 8;
        f32x4 wa0 = *(const f32x4*)(w1 + k0),       wa1 = *(const f32x4*)(w1 + k0 + 4);
        f32x4 wb0 = *(const f32x4*)(w1 + 256 + k0), wb1 = *(const f32x4*)(w1 + 256 + k0 + 4);
        f32x4 wc0 = *(const f32x4*)(w1 + 512 + k0), wc1 = *(const f32x4*)(w1 + 512 + k0 + 4);
        f32x4 bb0 = *(const f32x4*)(b1 + k0),       bb1 = *(const f32x4*)(b1 + k0 + 4);
#pragma unroll
        for (int jj = 0; jj < 4; ++jj) {
            float v0 = fmaf(in0, wa0[jj], fmaf(in1, wb0[jj], fmaf(in2, wc0[jj], bb0[jj])));
            float v1 = fmaf(in0, wa1[jj], fmaf(in1, wb1[jj], fmaf(in2, wc1[jj], bb1[jj])));
            hv[c8][jj]     = f2bf(fmaxf(v0, 0.f));
            hv[c8][jj + 4] = f2bf(fmaxf(v1, 0.f));
        }
    }
    // fragment-major H1 write: hv[c8] -> step s=2*wave+(c8>>2), chunk c8&3
#pragma unroll
    for (int c8 = 0; c8 < 8; ++c8)
        *(short8*)(&HhF[((2 * wave + (c8 >> 2)) * 4 + (c8 & 3)) * 512 + lane * 8]) = hv[c8];
    __builtin_amdgcn_sched_barrier(0);   // pin: H1 loads stay above gather

    // --- youngest vmem: F row gather DMA + own-row bias. Nothing after
    //     this waits on vmcnt until the post-loop __syncthreads. ---
    const short* Fb = F + (long)b * 4096 * FROW;
    const short fbs = Fb[(long)lin * FROW + 256];
#pragma unroll
    for (int j = 0; j < 8; ++j) {
        const int r = 2 * (wave * 8 + j) + (lane >> 5);
        const int linr = __shfl(lin, r, 64);
        const int colb = ((lane & 31) * 16) ^ ((r & 7) << 4);
        glld16(Fb + (long)linr * FROW + (colb >> 1), &FLds[(wave * 8 + j) * 512]);
    }
    __builtin_amdgcn_sched_barrier(0);   // pin: gather issues stay here

    barrier_lds();   // HhF visible (lgkm only); gather stays in flight

    // --- H2^T MFMA loop: ZERO vmem inside ---
    f32x4 acc2[4][4];
#pragma unroll
    for (int i = 0; i < 4; ++i)
#pragma unroll
        for (int ms = 0; ms < 4; ++ms) acc2[i][ms] = (f32x4){0.f, 0.f, 0.f, 0.f};

#pragma unroll
    for (int s = 0; s < 8; ++s) {
        short8 hf[4];
#pragma unroll
        for (int ms = 0; ms < 4; ++ms)
            hf[ms] = *(const short8*)(&HhF[(s * 4 + quad) * 512 + (ms * 16 + ln16) * 8]);
#pragma unroll
        for (int i = 0; i < 4; ++i)
#pragma unroll
            for (int ms = 0; ms < 4; ++ms)
                acc2[i][ms] = __builtin_amdgcn_mfma_f32_16x16x32_bf16(wbuf[s][i], hf[ms], acc2[i][ms], 0, 0, 0);
    }

    __syncthreads();   // drains gather (covered by the whole loop)

    // --- combine: pred[m] += relu(H2[n][m]+b2[n]) * F[lin[m]][n] ---
    f32x4 b2q[4];      // loaded late: gather already drained, no chaining cost
#pragma unroll
    for (int i = 0; i < 4; ++i)
        b2q[i] = *(const f32x4*)(b2v + wave * 64 + i * 16 + quad * 4);

    const float fbv = bf2f(fbs);
    float part[4] = {0.f, 0.f, 0.f, 0.f};
    const char* FLb = (const char*)FLds;
#pragma unroll
    for (int ms = 0; ms < 4; ++ms) {
        const int r = ms * 16 + ln16;
        const int xr = (r & 7) << 4;
        const int rb = r * 512;
#pragma unroll
        for (int i = 0; i < 4; ++i) {
            sv4 fvv = *(const sv4*)(FLb + rb + ((wave * 128 + i * 32 + quad * 8) ^ xr));
#pragma unroll
            for (int r4 = 0; r4 < 4; ++r4)
                part[ms] = fmaf(fmaxf(acc2[i][ms][r4] + b2q[i][r4], 0.f), bf2f(fvv[r4]), part[ms]);
        }
    }
#pragma unroll
    for (int ms = 0; ms < 4; ++ms) {
        part[ms] += __shfl_xor(part[ms], 16, 64);
        part[ms] += __shfl_xor(part[ms], 32, 64);
    }
    barrier_lds();                        // all FLds reads done before aliasing
    float* red = (float*)FLds;            // red[64][4] aliased into FLds
    if (quad == 0) {
#pragma unroll
        for (int ms = 0; ms < 4; ++ms) red[(ms * 16 + ln16) * 4 + wave] = part[ms];
    }
    barrier_lds();
    if (t < 64)
        out[qbase + t] = red[t * 4 + 0] + red[t * 4 + 1] + red[t * 4 + 2] + red[t * 4 + 3] + fbv;
}

// ---------------------------------------------------------------------------
extern "C" void kernel_launch(void* const* d_in, const int* in_sizes, int n_in,
                              void* d_out, int out_size, void* d_ws, size_t ws_size,
                              hipStream_t stream) {
    const float* feat  = (const float*)d_in[0];
    const float* coord = (const float*)d_in[1];
    const float* cell  = (const float*)d_in[2];
    const float* w1    = (const float*)d_in[3];
    const float* b1    = (const float*)d_in[4];
    const float* w2    = (const float*)d_in[5];
    const float* b2    = (const float*)d_in[6];
    const float* w3    = (const float*)d_in[7];
    const float* b3    = (const float*)d_in[8];
    float* out = (float*)d_out;

    char* ws = (char*)d_ws;
    short* w3cB  = (short*)(ws);                       // 72*2176*2      = 313,344
    short* w2cB  = (short*)(ws + 313344);              // 32*2048*2      = 131,072
    short* featT = (short*)(ws + 444416);              // 16*66*66*64*2  = 8,921,088
    short* F     = (short*)(ws + 9365504);             // 16*4096*264*2  = 34,603,008
    (void)ws_size; (void)in_sizes; (void)n_in; (void)out_size;

    prep_transpose_k<<<BB * HT, 256, 0, stream>>>(feat, w2, w3, b3, featT, w3cB, w2cB);
    conv_k<<<BB * HH, 256, 0, stream>>>(featT, w3cB, F);
    mlp_k<<<(BB * QQ) / 64, 256, 0, stream>>>(coord, cell, w1, b1, b2, w2cB, F, out);
}